// Round 5
// baseline (318.344 us; speedup 1.0000x reference)
//
#include <hip/hip_runtime.h>
#include <cstddef>
#include <cstdint>

#define IN_DIM 256
#define H_DIM  128
#define C_DIM  40
#define BM     128
#define BK     64
#define LDT    72    // ushort stride, phase-1 A/B tiles (144 B rows, measured 0 conflicts)
#define LDH    136   // ushort stride, phase-2 h / w2 tiles (272 B rows, same bank class)
#define PAD_C  64    // padded column count for bf16 intermediates (1 cache line/row)

typedef short bf16x8 __attribute__((ext_vector_type(8)));
typedef float f32x16 __attribute__((ext_vector_type(16)));
typedef float f32x4  __attribute__((ext_vector_type(4)));
typedef uint  u32x4  __attribute__((ext_vector_type(4)));

__device__ __forceinline__ ushort f2bf(float f) {   // RNE fp32 -> bf16
  uint u = __builtin_bit_cast(uint, f);
  u += 0x7fffu + ((u >> 16) & 1u);
  return (ushort)(u >> 16);
}
__device__ __forceinline__ float bf2f(uint s) {     // low 16 bits -> f32
  uint u = s << 16;
  return __builtin_bit_cast(float, u);
}

// ---------------------------------------------------------------------------
// CSR row_ptr from sorted edge_dst (lower_bound per node).
// ---------------------------------------------------------------------------
__global__ void build_row_ptr_kernel(const int* __restrict__ dst, int E,
                                     int* __restrict__ row_ptr, int n1) {
  int n = blockIdx.x * blockDim.x + threadIdx.x;
  if (n >= n1) return;
  int lo = 0, hi = E;
  while (lo < hi) {
    int mid = (lo + hi) >> 1;
    if (dst[mid] < n) lo = mid + 1; else hi = mid;
  }
  row_ptr[n] = lo;
}

// ---------------------------------------------------------------------------
// W1 [256][128] f32 -> w1t [128][256] bf16 ; W2 [128][40] f32 -> w2t [64][128]
// bf16 (n-major, zero-padded n=40..63 so GEMM2 pad cols come out zero).
// ---------------------------------------------------------------------------
__global__ void convert_weights_kernel(const float* __restrict__ W1,
                                       const float* __restrict__ W2,
                                       ushort* __restrict__ w1t,
                                       ushort* __restrict__ w2t) {
  int tid = blockIdx.x * blockDim.x + threadIdx.x;  // 0..40959
  if (tid < IN_DIM * H_DIM) {
    int k = tid >> 7, n = tid & 127;
    w1t[n * IN_DIM + k] = f2bf(W1[tid]);
  } else {
    int i = tid - IN_DIM * H_DIM;                   // 0..8191
    int n = i >> 7, k = i & 127;
    w2t[i] = (n < C_DIM) ? f2bf(W2[k * C_DIM + n]) : (ushort)0;
  }
}

// ---------------------------------------------------------------------------
// Fused dense MLP: z0[n][0:64] = pad(relu(feat[n] @ W1) @ W2) bf16.
// Block 256 thr (4 waves), 128-node tile, 52224 B LDS -> 3 blocks/CU.
// Phase 1: register double-buffered K-loop (prefetch iter k+1's feat/w1t at
//          loop top -> HBM latency overlaps convert/store/MFMA of iter k).
// Phase 2: relu(h) -> LDS A-layout rows, w2t -> LDS, GEMM2 via MFMA.
// ---------------------------------------------------------------------------
__global__ __launch_bounds__(256, 3) void fused_dense_kernel(
    const float* __restrict__ feat, const ushort* __restrict__ w1t,
    const ushort* __restrict__ w2t, ushort* __restrict__ z0, int N) {
  // phase1: A [128][LDT] + B [128][LDT]            = 36864 B
  // phase2: h [128][LDH] (34816 B) + w2 [64][LDH]  = 52224 B
  __shared__ __align__(16) ushort smem[26112];

  const int t = threadIdx.x;
  const int w = t >> 6, l = t & 63;
  const int nb = blockIdx.x * BM;

  f32x16 acc[4];
#pragma unroll
  for (int tn = 0; tn < 4; ++tn)
#pragma unroll
    for (int r = 0; r < 16; ++r) acc[tn][r] = 0.f;

  // staging assignment: thread -> (row 0..127, k-half 0/32)
  const int srow = t >> 1;
  const int skh  = (t & 1) << 5;
  int grow = nb + srow; if (grow >= N) grow = N - 1;
  const float*  fp = feat + (size_t)grow * IN_DIM + skh;
  const ushort* wp = w1t + (srow << 8) + skh;

  const ushort* Abase = smem + (w * 32 + (l & 31)) * LDT + ((l >> 5) << 3);
  const ushort* Bbase = smem + 128 * LDT + (l & 31) * LDT + ((l >> 5) << 3);
  uint4* adst = (uint4*)(smem + srow * LDT + skh);
  u32x4* bdst = (u32x4*)(smem + 128 * LDT + srow * LDT + skh);

  f32x4 fa[2][8];
  u32x4 wb[2][4];
#pragma unroll
  for (int i = 0; i < 8; ++i)
    fa[0][i] = __builtin_nontemporal_load((const f32x4*)fp + i);
#pragma unroll
  for (int i = 0; i < 4; ++i) wb[0][i] = ((const u32x4*)wp)[i];

#pragma unroll
  for (int kc = 0; kc < 4; ++kc) {
    const int cur = kc & 1, nxt = cur ^ 1;
    if (kc < 3) {                         // prefetch next K-chunk
      const f32x4* fn = (const f32x4*)(fp + (kc + 1) * BK);
      const u32x4* bn = (const u32x4*)(wp + (kc + 1) * BK);
#pragma unroll
      for (int i = 0; i < 8; ++i) fa[nxt][i] = __builtin_nontemporal_load(fn + i);
#pragma unroll
      for (int i = 0; i < 4; ++i) wb[nxt][i] = bn[i];
    }
    // convert + store current chunk to LDS
#pragma unroll
    for (int i = 0; i < 4; ++i) {
      f32x4 v0 = fa[cur][2 * i], v1 = fa[cur][2 * i + 1];
      uint4 pk;
      pk.x = (uint)f2bf(v0[0]) | ((uint)f2bf(v0[1]) << 16);
      pk.y = (uint)f2bf(v0[2]) | ((uint)f2bf(v0[3]) << 16);
      pk.z = (uint)f2bf(v1[0]) | ((uint)f2bf(v1[1]) << 16);
      pk.w = (uint)f2bf(v1[2]) | ((uint)f2bf(v1[3]) << 16);
      adst[i] = pk;
    }
#pragma unroll
    for (int i = 0; i < 4; ++i) bdst[i] = wb[cur][i];
    __syncthreads();

#pragma unroll
    for (int ks = 0; ks < 4; ++ks) {
      bf16x8 af = *(const bf16x8*)(Abase + ks * 16);
#pragma unroll
      for (int tn = 0; tn < 4; ++tn) {
        bf16x8 bfr = *(const bf16x8*)(Bbase + tn * 32 * LDT + ks * 16);
        acc[tn] = __builtin_amdgcn_mfma_f32_32x32x16_bf16(af, bfr, acc[tn], 0, 0, 0);
      }
    }
    __syncthreads();
  }

  // ---- phase 2: relu(h) -> LDS rows [node][k], C-layout: col=l&31, node=(r&3)+8*(r>>2)+4*(l>>5)
#pragma unroll
  for (int tn = 0; tn < 4; ++tn) {
    int col = tn * 32 + (l & 31);
#pragma unroll
    for (int r = 0; r < 16; ++r) {
      int nodeLoc = (r & 3) + 8 * (r >> 2) + 4 * (l >> 5) + 32 * w;
      float v = acc[tn][r];
      smem[nodeLoc * LDH + col] = f2bf(v > 0.f ? v : 0.f);
    }
  }
  // stage w2t [64][128] -> LDS [64][LDH]: thread t copies 32 ushorts (4 uint4)
  {
    int row = t >> 2, c4 = (t & 3) << 5;
    const uint4* src = (const uint4*)(w2t + row * H_DIM + c4);
    uint4* dst = (uint4*)(smem + 128 * LDH + row * LDH + c4);
    dst[0] = src[0];
    dst[1] = src[1];
    dst[2] = src[2];
    dst[3] = src[3];
  }
  __syncthreads();

  // GEMM2: wave w -> nodes 32w..+31, n-tiles {0..31, 32..63}, K=128
  f32x16 acc2[2];
#pragma unroll
  for (int tn = 0; tn < 2; ++tn)
#pragma unroll
    for (int r = 0; r < 16; ++r) acc2[tn][r] = 0.f;

  const ushort* Hbase  = smem + (w * 32 + (l & 31)) * LDH + ((l >> 5) << 3);
  const ushort* W2base = smem + 128 * LDH + (l & 31) * LDH + ((l >> 5) << 3);
#pragma unroll
  for (int kb = 0; kb < 8; ++kb) {
    bf16x8 af = *(const bf16x8*)(Hbase + kb * 16);
#pragma unroll
    for (int tn = 0; tn < 2; ++tn) {
      bf16x8 bfr = *(const bf16x8*)(W2base + tn * 32 * LDH + kb * 16);
      acc2[tn] = __builtin_amdgcn_mfma_f32_32x32x16_bf16(af, bfr, acc2[tn], 0, 0, 0);
    }
  }

  // store z0 (pad cols 40..63 are zero because w2t rows 40..63 are zero)
#pragma unroll
  for (int tn = 0; tn < 2; ++tn) {
    int col = tn * 32 + (l & 31);
#pragma unroll
    for (int r = 0; r < 16; ++r) {
      int node = nb + 32 * w + (r & 3) + 8 * (r >> 2) + 4 * (l >> 5);
      if (node < N) z0[(size_t)node * PAD_C + col] = f2bf(acc2[tn][r]);
    }
  }
}

// ---------------------------------------------------------------------------
// SPMM (CSR, dst-sorted): 2 nodes per wave (half-wave each). Within a half:
// h = edge slot 0..3, j = col oct 0..7; lane loads dwordx4 = 8 bf16 cols of
// slot h's source row -> 4 edges x full 128-B row per instr per node.
// 2-level butterfly (xor 8, 16) reduces slots. Edge/row_ptr streams use
// nontemporal loads so they don't evict x rows from L2.
// ---------------------------------------------------------------------------
__global__ __launch_bounds__(256) void spmm_kernel(
    const int* __restrict__ row_ptr, const int* __restrict__ esrc,
    const float* __restrict__ eval, const ushort* __restrict__ x,
    ushort* __restrict__ zb, float* __restrict__ zf, int N, int out_f32) {
  const int lane = threadIdx.x & 63;
  const int wv   = threadIdx.x >> 6;      // wave in block: 0..3
  const int sub  = lane >> 5;             // node within wave: 0..1
  const int h    = (lane >> 3) & 3;       // edge slot
  const int j    = lane & 7;              // col oct: cols 8j..8j+7

  int node = blockIdx.x * 8 + wv * 2 + sub;
  const bool valid = node < N;
  if (!valid) node = N - 1;

  int e   = __builtin_nontemporal_load(row_ptr + node);
  int end = __builtin_nontemporal_load(row_ptr + node + 1);

  float acc[8];
#pragma unroll
  for (int c = 0; c < 8; ++c) acc[c] = 0.f;

  for (; e + 4 <= end; e += 4) {
    int   s = __builtin_nontemporal_load(esrc + e + h);
    float v = __builtin_nontemporal_load(eval + e + h);
    u32x4 u = *(const u32x4*)(x + (size_t)s * PAD_C + j * 8);
    acc[0] = fmaf(v, bf2f(u.x & 0xffffu), acc[0]);
    acc[1] = fmaf(v, bf2f(u.x >> 16),     acc[1]);
    acc[2] = fmaf(v, bf2f(u.y & 0xffffu), acc[2]);
    acc[3] = fmaf(v, bf2f(u.y >> 16),     acc[3]);
    acc[4] = fmaf(v, bf2f(u.z & 0xffffu), acc[4]);
    acc[5] = fmaf(v, bf2f(u.z >> 16),     acc[5]);
    acc[6] = fmaf(v, bf2f(u.w & 0xffffu), acc[6]);
    acc[7] = fmaf(v, bf2f(u.w >> 16),     acc[7]);
  }
  if (e < end) {                          // tail: clamp slots past end, weight 0
    int ei = e + h;
    int ec = ei < end ? ei : end - 1;
    int   s  = __builtin_nontemporal_load(esrc + ec);
    float v0 = __builtin_nontemporal_load(eval + ec);
    float v  = ei < end ? v0 : 0.f;
    u32x4 u = *(const u32x4*)(x + (size_t)s * PAD_C + j * 8);
    acc[0] = fmaf(v, bf2f(u.x & 0xffffu), acc[0]);
    acc[1] = fmaf(v, bf2f(u.x >> 16),     acc[1]);
    acc[2] = fmaf(v, bf2f(u.y & 0xffffu), acc[2]);
    acc[3] = fmaf(v, bf2f(u.y >> 16),     acc[3]);
    acc[4] = fmaf(v, bf2f(u.z & 0xffffu), acc[4]);
    acc[5] = fmaf(v, bf2f(u.z >> 16),     acc[5]);
    acc[6] = fmaf(v, bf2f(u.w & 0xffffu), acc[6]);
    acc[7] = fmaf(v, bf2f(u.w >> 16),     acc[7]);
  }

  // reduce across the 4 edge slots (lane bits 3,4 — stays within half-wave)
#pragma unroll
  for (int c = 0; c < 8; ++c) acc[c] += __shfl_xor(acc[c], 8);
#pragma unroll
  for (int c = 0; c < 8; ++c) acc[c] += __shfl_xor(acc[c], 16);

  if (valid && h == 0) {
    if (out_f32) {
      if (j < 5) {                        // cols 0..39
        float4 o0 = {acc[0], acc[1], acc[2], acc[3]};
        float4 o1 = {acc[4], acc[5], acc[6], acc[7]};
        float* p = zf + (size_t)node * C_DIM + j * 8;
        *(float4*)(p + 0) = o0;
        *(float4*)(p + 4) = o1;
      }
    } else {                              // cols 0..63 (pads stay zero)
      uint4 p;
      p.x = (uint)f2bf(acc[0]) | ((uint)f2bf(acc[1]) << 16);
      p.y = (uint)f2bf(acc[2]) | ((uint)f2bf(acc[3]) << 16);
      p.z = (uint)f2bf(acc[4]) | ((uint)f2bf(acc[5]) << 16);
      p.w = (uint)f2bf(acc[6]) | ((uint)f2bf(acc[7]) << 16);
      *(uint4*)(zb + (size_t)node * PAD_C + j * 8) = p;
    }
  }
}

// ---------------------------------------------------------------------------
extern "C" void kernel_launch(void* const* d_in, const int* in_sizes, int n_in,
                              void* d_out, int out_size, void* d_ws, size_t ws_size,
                              hipStream_t stream) {
  const float* feat  = (const float*)d_in[0];
  const float* W1    = (const float*)d_in[1];
  const float* W2    = (const float*)d_in[2];
  const int*   esrc  = (const int*)d_in[3];
  const int*   edst  = (const int*)d_in[4];
  const float* evalp = (const float*)d_in[5];
  float* out = (float*)d_out;

  const int N = in_sizes[0] / IN_DIM;   // 100000
  const int E = in_sizes[3];            // 1600000

  // ws: z0 bf16 [N][64] | z1 bf16 [N][64] | w1t [128][256] | w2t [64][128] | row_ptr
  char* ws = (char*)d_ws;
  ushort* z0  = (ushort*)ws;
  ushort* z1  = (ushort*)(ws + (size_t)N * PAD_C * 2);
  ushort* w1t = (ushort*)(ws + (size_t)N * PAD_C * 4);
  ushort* w2t = w1t + IN_DIM * H_DIM;
  int* row_ptr = (int*)((char*)(w2t + PAD_C * H_DIM));

  build_row_ptr_kernel<<<(N + 256) / 256, 256, 0, stream>>>(edst, E, row_ptr, N + 1);
  convert_weights_kernel<<<(IN_DIM * H_DIM + PAD_C * H_DIM) / 256, 256, 0, stream>>>(
      W1, W2, w1t, w2t);
  fused_dense_kernel<<<(N + BM - 1) / BM, 256, 0, stream>>>(feat, w1t, w2t, z0, N);
  spmm_kernel<<<(N + 7) / 8, 256, 0, stream>>>(row_ptr, esrc, evalp, z0, z1, nullptr, N, 0);
  spmm_kernel<<<(N + 7) / 8, 256, 0, stream>>>(row_ptr, esrc, evalp, z1, nullptr, out, N, 1);
}

// Round 6
// 273.795 us; speedup vs baseline: 1.1627x; 1.1627x over previous
//
#include <hip/hip_runtime.h>
#include <cstddef>
#include <cstdint>

#define IN_DIM 256
#define H_DIM  128
#define C_DIM  40
#define BM     128
#define BK     64
#define LDT    72    // ushort stride, phase-1 A/B tiles (144 B rows, measured 0 conflicts)
#define LDH    136   // ushort stride, phase-2 h / w2 tiles (272 B rows, same bank class)
#define PAD_C  64    // padded column count for bf16 intermediates (1 cache line/row)

typedef short bf16x8 __attribute__((ext_vector_type(8)));
typedef float f32x16 __attribute__((ext_vector_type(16)));
typedef uint  u32x4  __attribute__((ext_vector_type(4)));

__device__ __forceinline__ ushort f2bf(float f) {   // RNE fp32 -> bf16
  uint u = __builtin_bit_cast(uint, f);
  u += 0x7fffu + ((u >> 16) & 1u);
  return (ushort)(u >> 16);
}
__device__ __forceinline__ float bf2f(uint s) {     // low 16 bits -> f32
  uint u = s << 16;
  return __builtin_bit_cast(float, u);
}
// packed fp32x2 -> bf16x2 (HW cvt if available; manual RNE fallback)
__device__ __forceinline__ uint pack2bf(float a, float b) {
#if __has_builtin(__builtin_amdgcn_cvt_pk_bf16_f32)
  typedef __bf16 bf16v2 __attribute__((ext_vector_type(2)));
  bf16v2 r = __builtin_amdgcn_cvt_pk_bf16_f32(a, b);
  return __builtin_bit_cast(uint, r);
#else
  return (uint)f2bf(a) | ((uint)f2bf(b) << 16);
#endif
}

// ---------------------------------------------------------------------------
// CSR row_ptr from sorted edge_dst (lower_bound per node).
// ---------------------------------------------------------------------------
__global__ void build_row_ptr_kernel(const int* __restrict__ dst, int E,
                                     int* __restrict__ row_ptr, int n1) {
  int n = blockIdx.x * blockDim.x + threadIdx.x;
  if (n >= n1) return;
  int lo = 0, hi = E;
  while (lo < hi) {
    int mid = (lo + hi) >> 1;
    if (dst[mid] < n) lo = mid + 1; else hi = mid;
  }
  row_ptr[n] = lo;
}

// ---------------------------------------------------------------------------
// W1 [256][128] f32 -> w1t [128][256] bf16 ; W2 [128][40] f32 -> w2t [64][128]
// bf16 (n-major, zero-padded n=40..63 so GEMM2 pad cols come out zero).
// ---------------------------------------------------------------------------
__global__ void convert_weights_kernel(const float* __restrict__ W1,
                                       const float* __restrict__ W2,
                                       ushort* __restrict__ w1t,
                                       ushort* __restrict__ w2t) {
  int tid = blockIdx.x * blockDim.x + threadIdx.x;  // 0..40959
  if (tid < IN_DIM * H_DIM) {
    int k = tid >> 7, n = tid & 127;
    w1t[n * IN_DIM + k] = f2bf(W1[tid]);
  } else {
    int i = tid - IN_DIM * H_DIM;                   // 0..8191
    int n = i >> 7, k = i & 127;
    w2t[i] = (n < C_DIM) ? f2bf(W2[k * C_DIM + n]) : (ushort)0;
  }
}

// ---------------------------------------------------------------------------
// Fused dense MLP: z0[n][0:64] = pad(relu(feat[n] @ W1) @ W2) bf16.
// Block 256 thr (4 waves), 128-node tile, 52224 B LDS -> 3 blocks/CU.
// Phase 1: h = feat @ W1 via mfma_32x32x16_bf16 (wave w: nodes 32w..+31,
//          4 col-tiles); HW packed cvt for fp32->bf16 staging.
// Phase 2: relu(h) -> LDS A-layout rows, w2t -> LDS, GEMM2 via MFMA.
// ---------------------------------------------------------------------------
__global__ __launch_bounds__(256, 3) void fused_dense_kernel(
    const float* __restrict__ feat, const ushort* __restrict__ w1t,
    const ushort* __restrict__ w2t, ushort* __restrict__ z0, int N) {
  // phase1: A [128][LDT] + B [128][LDT]            = 36864 B
  // phase2: h [128][LDH] (34816 B) + w2 [64][LDH]  = 52224 B
  __shared__ __align__(16) ushort smem[26112];

  const int t = threadIdx.x;
  const int w = t >> 6, l = t & 63;
  const int nb = blockIdx.x * BM;

  f32x16 acc[4];
#pragma unroll
  for (int tn = 0; tn < 4; ++tn)
#pragma unroll
    for (int r = 0; r < 16; ++r) acc[tn][r] = 0.f;

  // staging assignment: thread -> (row 0..127, k-half 0/32)
  const int srow = t >> 1;
  const int skh  = (t & 1) << 5;
  int grow = nb + srow; if (grow >= N) grow = N - 1;
  const float*  fp = feat + (size_t)grow * IN_DIM + skh;
  const ushort* wp = w1t + (srow << 8) + skh;

  const ushort* Abase = smem + (w * 32 + (l & 31)) * LDT + ((l >> 5) << 3);
  const ushort* Bbase = smem + 128 * LDT + (l & 31) * LDT + ((l >> 5) << 3);

  for (int kc = 0; kc < IN_DIM; kc += BK) {
    const float4* f4 = (const float4*)(fp + kc);
    uint4* adst = (uint4*)(smem + srow * LDT + skh);
#pragma unroll
    for (int i = 0; i < 4; ++i) {
      float4 v0 = f4[2 * i], v1 = f4[2 * i + 1];
      uint4 pk;
      pk.x = pack2bf(v0.x, v0.y);
      pk.y = pack2bf(v0.z, v0.w);
      pk.z = pack2bf(v1.x, v1.y);
      pk.w = pack2bf(v1.z, v1.w);
      adst[i] = pk;
    }
    const uint4* bsrc = (const uint4*)(wp + kc);
    uint4* bdst = (uint4*)(smem + 128 * LDT + srow * LDT + skh);
#pragma unroll
    for (int i = 0; i < 4; ++i) bdst[i] = bsrc[i];
    __syncthreads();

#pragma unroll
    for (int ks = 0; ks < 4; ++ks) {
      bf16x8 af = *(const bf16x8*)(Abase + ks * 16);
#pragma unroll
      for (int tn = 0; tn < 4; ++tn) {
        bf16x8 bfr = *(const bf16x8*)(Bbase + tn * 32 * LDT + ks * 16);
        acc[tn] = __builtin_amdgcn_mfma_f32_32x32x16_bf16(af, bfr, acc[tn], 0, 0, 0);
      }
    }
    __syncthreads();
  }

  // ---- phase 2: relu(h) -> LDS rows [node][k], C-layout: col=l&31, node=(r&3)+8*(r>>2)+4*(l>>5)
#pragma unroll
  for (int tn = 0; tn < 4; ++tn) {
    int col = tn * 32 + (l & 31);
#pragma unroll
    for (int r = 0; r < 16; ++r) {
      int nodeLoc = (r & 3) + 8 * (r >> 2) + 4 * (l >> 5) + 32 * w;
      float v = acc[tn][r];
      smem[nodeLoc * LDH + col] = f2bf(v > 0.f ? v : 0.f);
    }
  }
  // stage w2t [64][128] -> LDS [64][LDH]: thread t copies 32 ushorts (4 uint4)
  {
    int row = t >> 2, c4 = (t & 3) << 5;
    const uint4* src = (const uint4*)(w2t + row * H_DIM + c4);
    uint4* dst = (uint4*)(smem + 128 * LDH + row * LDH + c4);
    dst[0] = src[0];
    dst[1] = src[1];
    dst[2] = src[2];
    dst[3] = src[3];
  }
  __syncthreads();

  // GEMM2: wave w -> nodes 32w..+31, n-tiles {0..31, 32..63}, K=128
  f32x16 acc2[2];
#pragma unroll
  for (int tn = 0; tn < 2; ++tn)
#pragma unroll
    for (int r = 0; r < 16; ++r) acc2[tn][r] = 0.f;

  const ushort* Hbase  = smem + (w * 32 + (l & 31)) * LDH + ((l >> 5) << 3);
  const ushort* W2base = smem + 128 * LDH + (l & 31) * LDH + ((l >> 5) << 3);
#pragma unroll
  for (int kb = 0; kb < 8; ++kb) {
    bf16x8 af = *(const bf16x8*)(Hbase + kb * 16);
#pragma unroll
    for (int tn = 0; tn < 2; ++tn) {
      bf16x8 bfr = *(const bf16x8*)(W2base + tn * 32 * LDH + kb * 16);
      acc2[tn] = __builtin_amdgcn_mfma_f32_32x32x16_bf16(af, bfr, acc2[tn], 0, 0, 0);
    }
  }

  // store z0 (pad cols 40..63 are zero because w2t rows 40..63 are zero)
#pragma unroll
  for (int tn = 0; tn < 2; ++tn) {
    int col = tn * 32 + (l & 31);
#pragma unroll
    for (int r = 0; r < 16; ++r) {
      int node = nb + 32 * w + (r & 3) + 8 * (r >> 2) + 4 * (l >> 5);
      if (node < N) z0[(size_t)node * PAD_C + col] = f2bf(acc2[tn][r]);
    }
  }
}

// ---------------------------------------------------------------------------
// SPMM (CSR, dst-sorted): one wave per node. lane = 8*h + j (h = edge slot,
// j = col oct); lane loads dwordx4 = 8 bf16 cols of slot h's source row ->
// 8 full 128-B rows per instruction. Main loop unrolled x2 (16 edges/iter,
// 2 independent esrc->gather chains in flight). Butterfly-reduce slots.
// ---------------------------------------------------------------------------
__global__ __launch_bounds__(256) void spmm_kernel(
    const int* __restrict__ row_ptr, const int* __restrict__ esrc,
    const float* __restrict__ eval, const ushort* __restrict__ x,
    ushort* __restrict__ zb, float* __restrict__ zf, int N, int out_f32) {
  int node = (blockIdx.x << 2) + (threadIdx.x >> 6);
  if (node >= N) return;
  const int lane = threadIdx.x & 63;
  const int h = lane >> 3;          // edge slot
  const int j = lane & 7;           // col oct: cols 8j..8j+7

  int e   = row_ptr[node];
  int end = row_ptr[node + 1];

  float acc[8];
#pragma unroll
  for (int c = 0; c < 8; ++c) acc[c] = 0.f;

  // 16 edges per iteration: two independent gather chains
  for (; e + 16 <= end; e += 16) {
    int   s0 = esrc[e + h];
    int   s1 = esrc[e + 8 + h];
    float v0 = eval[e + h];
    float v1 = eval[e + 8 + h];
    u32x4 a = *(const u32x4*)(x + (size_t)s0 * PAD_C + j * 8);
    u32x4 b = *(const u32x4*)(x + (size_t)s1 * PAD_C + j * 8);
    acc[0] = fmaf(v0, bf2f(a.x & 0xffffu), acc[0]);
    acc[1] = fmaf(v0, bf2f(a.x >> 16),     acc[1]);
    acc[2] = fmaf(v0, bf2f(a.y & 0xffffu), acc[2]);
    acc[3] = fmaf(v0, bf2f(a.y >> 16),     acc[3]);
    acc[4] = fmaf(v0, bf2f(a.z & 0xffffu), acc[4]);
    acc[5] = fmaf(v0, bf2f(a.z >> 16),     acc[5]);
    acc[6] = fmaf(v0, bf2f(a.w & 0xffffu), acc[6]);
    acc[7] = fmaf(v0, bf2f(a.w >> 16),     acc[7]);
    acc[0] = fmaf(v1, bf2f(b.x & 0xffffu), acc[0]);
    acc[1] = fmaf(v1, bf2f(b.x >> 16),     acc[1]);
    acc[2] = fmaf(v1, bf2f(b.y & 0xffffu), acc[2]);
    acc[3] = fmaf(v1, bf2f(b.y >> 16),     acc[3]);
    acc[4] = fmaf(v1, bf2f(b.z & 0xffffu), acc[4]);
    acc[5] = fmaf(v1, bf2f(b.z >> 16),     acc[5]);
    acc[6] = fmaf(v1, bf2f(b.w & 0xffffu), acc[6]);
    acc[7] = fmaf(v1, bf2f(b.w >> 16),     acc[7]);
  }
  for (; e + 8 <= end; e += 8) {
    int   s = esrc[e + h];
    float v = eval[e + h];
    u32x4 u = *(const u32x4*)(x + (size_t)s * PAD_C + j * 8);
    acc[0] = fmaf(v, bf2f(u.x & 0xffffu), acc[0]);
    acc[1] = fmaf(v, bf2f(u.x >> 16),     acc[1]);
    acc[2] = fmaf(v, bf2f(u.y & 0xffffu), acc[2]);
    acc[3] = fmaf(v, bf2f(u.y >> 16),     acc[3]);
    acc[4] = fmaf(v, bf2f(u.z & 0xffffu), acc[4]);
    acc[5] = fmaf(v, bf2f(u.z >> 16),     acc[5]);
    acc[6] = fmaf(v, bf2f(u.w & 0xffffu), acc[6]);
    acc[7] = fmaf(v, bf2f(u.w >> 16),     acc[7]);
  }
  if (e < end) {                    // tail: clamp slots past the end, weight 0
    int ei = e + h;
    int ec = ei < end ? ei : end - 1;
    int   s  = esrc[ec];
    float v0 = eval[ec];
    float v  = ei < end ? v0 : 0.f;
    u32x4 u = *(const u32x4*)(x + (size_t)s * PAD_C + j * 8);
    acc[0] = fmaf(v, bf2f(u.x & 0xffffu), acc[0]);
    acc[1] = fmaf(v, bf2f(u.x >> 16),     acc[1]);
    acc[2] = fmaf(v, bf2f(u.y & 0xffffu), acc[2]);
    acc[3] = fmaf(v, bf2f(u.y >> 16),     acc[3]);
    acc[4] = fmaf(v, bf2f(u.z & 0xffffu), acc[4]);
    acc[5] = fmaf(v, bf2f(u.z >> 16),     acc[5]);
    acc[6] = fmaf(v, bf2f(u.w & 0xffffu), acc[6]);
    acc[7] = fmaf(v, bf2f(u.w >> 16),     acc[7]);
  }

  // reduce across the 8 edge slots (lane bits 3..5)
#pragma unroll
  for (int c = 0; c < 8; ++c) acc[c] += __shfl_xor(acc[c], 8);
#pragma unroll
  for (int c = 0; c < 8; ++c) acc[c] += __shfl_xor(acc[c], 16);
#pragma unroll
  for (int c = 0; c < 8; ++c) acc[c] += __shfl_xor(acc[c], 32);

  if (out_f32) {
    if (lane < 5) {                 // lanes 0..4: j=0..4 -> cols 0..39
      float4 o0 = {acc[0], acc[1], acc[2], acc[3]};
      float4 o1 = {acc[4], acc[5], acc[6], acc[7]};
      float* p = zf + (size_t)node * C_DIM + j * 8;
      *(float4*)(p + 0) = o0;
      *(float4*)(p + 4) = o1;
    }
  } else {
    if (lane < 8) {                 // lanes 0..7: j=0..7 -> cols 0..63
      uint4 p;
      p.x = (uint)f2bf(acc[0]) | ((uint)f2bf(acc[1]) << 16);
      p.y = (uint)f2bf(acc[2]) | ((uint)f2bf(acc[3]) << 16);
      p.z = (uint)f2bf(acc[4]) | ((uint)f2bf(acc[5]) << 16);
      p.w = (uint)f2bf(acc[6]) | ((uint)f2bf(acc[7]) << 16);
      *(uint4*)(zb + (size_t)node * PAD_C + j * 8) = p;
    }
  }
}

// ---------------------------------------------------------------------------
extern "C" void kernel_launch(void* const* d_in, const int* in_sizes, int n_in,
                              void* d_out, int out_size, void* d_ws, size_t ws_size,
                              hipStream_t stream) {
  const float* feat  = (const float*)d_in[0];
  const float* W1    = (const float*)d_in[1];
  const float* W2    = (const float*)d_in[2];
  const int*   esrc  = (const int*)d_in[3];
  const int*   edst  = (const int*)d_in[4];
  const float* evalp = (const float*)d_in[5];
  float* out = (float*)d_out;

  const int N = in_sizes[0] / IN_DIM;   // 100000
  const int E = in_sizes[3];            // 1600000

  // ws: z0 bf16 [N][64] | z1 bf16 [N][64] | w1t [128][256] | w2t [64][128] | row_ptr
  char* ws = (char*)d_ws;
  ushort* z0  = (ushort*)ws;
  ushort* z1  = (ushort*)(ws + (size_t)N * PAD_C * 2);
  ushort* w1t = (ushort*)(ws + (size_t)N * PAD_C * 4);
  ushort* w2t = w1t + IN_DIM * H_DIM;
  int* row_ptr = (int*)((char*)(w2t + PAD_C * H_DIM));

  build_row_ptr_kernel<<<(N + 256) / 256, 256, 0, stream>>>(edst, E, row_ptr, N + 1);
  convert_weights_kernel<<<(IN_DIM * H_DIM + PAD_C * H_DIM) / 256, 256, 0, stream>>>(
      W1, W2, w1t, w2t);
  fused_dense_kernel<<<(N + BM - 1) / BM, 256, 0, stream>>>(feat, w1t, w2t, z0, N);
  spmm_kernel<<<(N + 3) / 4, 256, 0, stream>>>(row_ptr, esrc, evalp, z0, z1, nullptr, N, 0);
  spmm_kernel<<<(N + 3) / 4, 256, 0, stream>>>(row_ptr, esrc, evalp, z1, nullptr, out, N, 1);
}